// Round 2
// baseline (406.796 us; speedup 1.0000x reference)
//
#include <hip/hip_runtime.h>
#include <math.h>

// Element-wise physics step, B = 8,388,608 rows.
// R1: 4 rows per thread -> all global traffic as aligned float4 (16 B/lane).
// Per thread: 5x float4 load (x), 2+2x float4 load (a,noise),
//             5x float4 store (next_x), 1x float4 store (reached).
// Numerics mirror numpy f32 op-by-op (no FMA contraction in critical chain).

__global__ __launch_bounds__(256) void step_kernel(
    const float* __restrict__ x,        // (B,5)
    const float* __restrict__ a,        // (B,2)
    const float* __restrict__ noise,    // (B,2)
    const float* __restrict__ pro_gains,          // (2,)
    const float* __restrict__ pro_noise_ln_vars,  // (2,)
    const float* __restrict__ goal_radius,        // (1,)
    float* __restrict__ out_next,       // (B,5) at d_out
    float* __restrict__ out_reach,      // (B,)  at d_out + 5*B
    int nquad)                          // B/4
{
    int t = blockIdx.x * blockDim.x + threadIdx.x;
    if (t >= nquad) return;

    // Uniform scalars.
    const float g0 = pro_gains[0];
    const float g1 = pro_gains[1];
    const float std0 = __fsqrt_rn(expf(pro_noise_ln_vars[0]));
    const float std1 = __fsqrt_rn(expf(pro_noise_ln_vars[1]));
    const float gr = goal_radius[0];

    const size_t st = (size_t)t;

    // ---- vectorized loads: 4 rows per thread ----
    float xf[20];
    {
        const float4* x4 = (const float4*)x + st * 5;
        #pragma unroll
        for (int k = 0; k < 5; ++k) {
            float4 v = x4[k];
            xf[4*k+0] = v.x; xf[4*k+1] = v.y; xf[4*k+2] = v.z; xf[4*k+3] = v.w;
        }
    }
    float af[8], nf[8];
    {
        const float4* a4 = (const float4*)a + st * 2;
        const float4* n4 = (const float4*)noise + st * 2;
        #pragma unroll
        for (int k = 0; k < 2; ++k) {
            float4 v = a4[k];
            af[4*k+0] = v.x; af[4*k+1] = v.y; af[4*k+2] = v.z; af[4*k+3] = v.w;
            float4 w = n4[k];
            nf[4*k+0] = w.x; nf[4*k+1] = w.y; nf[4*k+2] = w.z; nf[4*k+3] = w.w;
        }
    }

    float of[20];   // next_x for 4 rows
    float rf[4];    // reached for 4 rows

    const float DT    = 0.1f;
    const float PI_F  = 3.14159265358979323846f;  // rounds to 3.14159274f
    const float TWOPI = 6.283185307179586f;       // rounds to 6.2831855f

    #pragma unroll
    for (int r = 0; r < 4; ++r) {
        const float px0  = xf[5*r + 0];
        const float py0  = xf[5*r + 1];
        const float ang0 = xf[5*r + 2];
        const float a0 = af[2*r + 0], a1 = af[2*r + 1];
        const float n0 = nf[2*r + 0], n1 = nf[2*r + 1];

        // vel = g0*a0 + std0*n0 ; ang_vel = g1*a1 + std1*n1 (numpy order, no fma)
        const float vel     = __fadd_rn(__fmul_rn(g0, a0), __fmul_rn(std0, n0));
        const float ang_vel = __fadd_rn(__fmul_rn(g1, a1), __fmul_rn(std1, n1));

        // ang = mod(ang0 + ang_vel*DT + pi, 2pi) - pi (numpy mod: sign of divisor)
        const float tt = __fadd_rn(ang0, __fmul_rn(ang_vel, DT));
        const float tp = __fadd_rn(tt, PI_F);
        float m = fmodf(tp, TWOPI);
        if (m < 0.0f) m = __fadd_rn(m, TWOPI);
        const float ang = __fsub_rn(m, PI_F);

        float s, c;
        sincosf(ang, &s, &c);  // accurate variant, matches np closely

        float px = __fadd_rn(px0, __fmul_rn(__fmul_rn(vel, c), DT));
        px = fminf(fmaxf(px, -1.0f), 1.0f);
        float py = __fadd_rn(py0, __fmul_rn(__fmul_rn(vel, s), DT));
        py = fminf(fmaxf(py, -1.0f), 1.0f);

        const float r2 = __fadd_rn(__fmul_rn(px, px), __fmul_rn(py, py));
        const float rr = __fsqrt_rn(r2);

        of[5*r + 0] = px;
        of[5*r + 1] = py;
        of[5*r + 2] = ang;
        of[5*r + 3] = vel;
        of[5*r + 4] = ang_vel;
        rf[r] = (rr <= gr) ? 1.0f : 0.0f;
    }

    // ---- vectorized stores ----
    {
        float4* o4 = (float4*)out_next + st * 5;
        #pragma unroll
        for (int k = 0; k < 5; ++k) {
            float4 v;
            v.x = of[4*k+0]; v.y = of[4*k+1]; v.z = of[4*k+2]; v.w = of[4*k+3];
            o4[k] = v;
        }
        float4 rv; rv.x = rf[0]; rv.y = rf[1]; rv.z = rf[2]; rv.w = rf[3];
        ((float4*)out_reach)[st] = rv;
    }
}

extern "C" void kernel_launch(void* const* d_in, const int* in_sizes, int n_in,
                              void* d_out, int out_size, void* d_ws, size_t ws_size,
                              hipStream_t stream) {
    const float* x      = (const float*)d_in[0];
    const float* a      = (const float*)d_in[1];
    const float* noise  = (const float*)d_in[2];
    const float* gains  = (const float*)d_in[3];
    const float* lnvars = (const float*)d_in[4];
    const float* gradius= (const float*)d_in[5];

    const int n = in_sizes[0] / 5;            // B (divisible by 4)
    float* out_next  = (float*)d_out;         // B*5 floats
    float* out_reach = (float*)d_out + (size_t)n * 5;  // B floats

    const int nquad = n / 4;
    const int block = 256;
    const int grid = (nquad + block - 1) / block;
    step_kernel<<<grid, block, 0, stream>>>(x, a, noise, gains, lnvars, gradius,
                                            out_next, out_reach, nquad);
}